// Round 6
// baseline (129.346 us; speedup 1.0000x reference)
//
#include <hip/hip_runtime.h>
#include <math.h>

// Problem constants (fixed by setup_inputs): N src points, M targets, D=3.
constexpr int N_SRC = 16384;
constexpr int M_TAR = 16384;

// R11: occupancy 4 -> 8 waves/SIMD; instruction stream held bit-identical.
// Evidence trail: duration is pinned at ~40us and responds to instruction-
// count cuts with slope only ~0.3-0.4 (R9: -22% stream -> -6% dur; R10:
// SGPR coefs -> -1us). VALUBusy's gfx94x fallback formula double-counts on
// SIMD-32, so R9's "25us busy" was ~12.6us real issue = the 12.0us floor.
// The kernel is ~70% STALLED, not issue-bound: at 4 waves/SIMD (64KB LDS
// double-buffer capped 2 blocks/CU x 8 waves) every tile's lgkmcnt drain +
// __syncthreads has nothing to hide behind.
// Change: TILE=1024 (CHUNKS=512, 2 rows/tile, 16 tiles), TPB=1024
// -> 2 blocks/CU x 16 waves = 32 waves/CU = 8 waves/SIMD (HW max).
// Per-pair cost unchanged: 6 v_fma_f32 + 1 v_min3_f32 per source-pair
// = 3.5 VALU ops/pair; coefficients remain SGPR via readfirstlane.
constexpr int BLOCKS = 512;            // 32 targets per block
constexpr int TPB = 1024;              // 16 waves
constexpr int CHUNKS = 512;            // chunk = tid & 511
constexpr int TILE = 1024;             // sources per LDS tile (16 KB float4)
constexpr int TILES = N_SRC / TILE;    // 16
constexpr int TPT = 16;                // targets per wave-half
constexpr int NROWS = N_SRC / CHUNKS;  // 32 rows per chunk overall

__global__ void zero_out(float* __restrict__ out) {
    if (threadIdx.x == 0) out[0] = 0.0f;  // d_out poisoned 0xAA each launch
}

// best = min(best, e0, e1) in one instruction (inputs never NaN here)
__device__ __forceinline__ void min3(float& b, float e0, float e1) {
    asm("v_min3_f32 %0, %0, %1, %2"
        : "+v"(b) : "v"(e0), "v"(e1));
}

// wave-uniform float -> SGPR (bit-exact; all lanes hold the same value)
__device__ __forceinline__ float to_sgpr(float x) {
    return __uint_as_float(
        (unsigned)__builtin_amdgcn_readfirstlane((int)__float_as_uint(x)));
}

__global__
__attribute__((amdgpu_flat_work_group_size(TPB, TPB)))
__attribute__((amdgpu_waves_per_eu(8, 8)))
void nn12(const float* __restrict__ src,
          const float* __restrict__ tar,
          float* __restrict__ out) {
    // 64 KB: main loop double-buffers in [0, 2*TILE); tail reuses all of it
    // as fv[32][512] (64 KB of floats).
    __shared__ float4 lds[4 * TILE];

    const int tid   = threadIdx.x;
    const int g     = tid >> 9;     // 0..1: wave-uniform target half
    const int chunk = tid & 511;    // 0..511: source slice
    const int tbase = blockIdx.x * 32;

    // 16 targets per wave-half (uniform across lanes) -> coefs in SGPRs.
    float txm2[TPT], tym2[TPT], tzm2[TPT], best[TPT];
#pragma unroll
    for (int k = 0; k < TPT; ++k) {
        int T = tbase + g * TPT + k;
        txm2[k] = to_sgpr(-2.0f * tar[3 * T + 0]);
        tym2[k] = to_sgpr(-2.0f * tar[3 * T + 1]);
        tzm2[k] = to_sgpr(-2.0f * tar[3 * T + 2]);
        best[k] = INFINITY;
    }

    // ---- prolog: stage tile 0 (w = ||s||^2; exact op order matters: the
    // tail rescan replicates fmaf(x,x,fmaf(y,y,z*z)) bit-for-bit)
    {
        const float* q = src + 3 * tid;
        float x = q[0], y = q[1], z = q[2];
        lds[tid] = make_float4(x, y, z, fmaf(x, x, fmaf(y, y, z * z)));
    }
    __syncthreads();

    auto compute = [&](int cb) {
        float4 s0 = lds[cb + chunk];
        float4 s1 = lds[cb + CHUNKS + chunk];
#pragma unroll
        for (int k = 0; k < TPT; ++k) {
            float t0 = fmaf(s0.z, tzm2[k], s0.w);   // 1 SGPR operand each
            t0 = fmaf(s0.y, tym2[k], t0);
            t0 = fmaf(s0.x, txm2[k], t0);
            float t1 = fmaf(s1.z, tzm2[k], s1.w);
            t1 = fmaf(s1.y, tym2[k], t1);
            t1 = fmaf(s1.x, txm2[k], t1);
            min3(best[k], t0, t1);   // 7 VALU per 2 pairs = 3.5/pair
        }
    };

    // ---- pipelined main loop: prefetch tl+1, compute tl, write tl+1
#pragma unroll 1
    for (int tl = 0; tl < TILES - 1; ++tl) {
        const float* q = src + 3 * ((tl + 1) * TILE + tid);
        float px = q[0], py = q[1], pz = q[2];
        __builtin_amdgcn_sched_barrier(0);  // keep load issues above compute

        compute((tl & 1) * TILE);

        const int wb = ((tl + 1) & 1) * TILE;
        lds[wb + tid] = make_float4(px, py, pz,
                                    fmaf(px, px, fmaf(py, py, pz * pz)));
        __syncthreads();  // publishes writes for tl+1; retires reads of tl
    }
    compute(((TILES - 1) & 1) * TILE);

    // ---- tail: per-target reduce (value, chunk), then rescan winning chunk
    __syncthreads();                     // all compute reads of lds done
    float* fv = (float*)lds;             // [32][512] raw best values (64 KB)
#pragma unroll
    for (int k = 0; k < TPT; ++k) {
        fv[(g * TPT + k) * CHUNKS + chunk] = best[k];
    }
    __syncthreads();

    const int tprime = tid >> 5;   // 0..31: target this 32-lane group reduces
    const int sub    = tid & 31;
    float bv = fv[tprime * CHUNKS + sub];
    int   bc = sub;                // winning chunk id
#pragma unroll
    for (int m = 1; m < CHUNKS / 32; ++m) {
        float v = fv[tprime * CHUNKS + sub + 32 * m];
        if (v < bv) { bv = v; bc = sub + 32 * m; }
    }
#pragma unroll
    for (int s = 16; s >= 1; s >>= 1) {  // xor<32 stays in the aligned group
        float vv = __shfl_xor(bv, s, 64);
        int   cc = __shfl_xor(bc, s, 64);
        if (vv < bv) { bv = vv; bc = cc; }
    }
    // all 32 lanes of the group now hold (bv, bc) for target tprime.

    // ---- rescan: find the row in chunk bc whose value bit-matches bv.
    // Same fma chain as pass 1 -> the winning row reproduces bv exactly.
    const int T = tbase + tprime;
    const float tx = tar[3 * T + 0], ty = tar[3 * T + 1], tz = tar[3 * T + 2];
    const float rxm2 = -2.0f * tx, rym2 = -2.0f * ty, rzm2 = -2.0f * tz;
    int myrow;
    {
        int j = sub * CHUNKS + bc;       // row = sub (0..31), one row/lane
        const float* q = src + 3 * j;
        float x = q[0], y = q[1], z = q[2];
        float w = fmaf(x, x, fmaf(y, y, z * z));
        float v = fmaf(z, rzm2, w);
        v = fmaf(y, rym2, v);
        v = fmaf(x, rxm2, v);
        myrow = (v == bv) ? sub : NROWS;
    }
#pragma unroll
    for (int s = 16; s >= 1; s >>= 1) {
        int r2 = __shfl_xor(myrow, s, 64);
        if (r2 < myrow) myrow = r2;
    }
    __syncthreads();  // done reading fv; safe to overwrite fv[0..31]

    if (sub == 0) {
        int j = myrow * CHUNKS + bc;
        // exact loss term from the winning index (reference formula)
        float dx = src[3 * j + 0] - tx;
        float dy = src[3 * j + 1] - ty;
        float dz = src[3 * j + 2] - tz;
        fv[tprime] = 0.5f * fmaf(dx, dx, fmaf(dy, dy, dz * dz));
    }
    __syncthreads();
    if (tid == 0) {
        float ssum = 0.0f;
#pragma unroll
        for (int i = 0; i < 32; ++i) ssum += fv[i];
        atomicAdd(out, ssum);  // device-scope, cross-XCD safe
    }
}

extern "C" void kernel_launch(void* const* d_in, const int* in_sizes, int n_in,
                              void* d_out, int out_size, void* d_ws, size_t ws_size,
                              hipStream_t stream) {
    const float* src = (const float*)d_in[0];  // src_V [N,3] fp32
    const float* tar = (const float*)d_in[1];  // tar_V [M,3] fp32
    float* out = (float*)d_out;                // scalar loss fp32
    (void)d_ws; (void)ws_size;

    zero_out<<<1, 64, 0, stream>>>(out);
    nn12<<<BLOCKS, TPB, 0, stream>>>(src, tar, out);
}

// Round 7
// 92.241 us; speedup vs baseline: 1.4023x; 1.4023x over previous
//
#include <hip/hip_runtime.h>
#include <math.h>

// Problem constants (fixed by setup_inputs): N src points, M targets, D=3.
constexpr int N_SRC = 16384;
constexpr int M_TAR = 16384;

// R12: R11's structure (8 waves/SIMD) with the register-budget repair.
// R11 evidence: amdgpu_waves_per_eu(8,8) drove the allocator to VGPR=32/
// SGPR=32 and spilled the working set to scratch -> FETCH_SIZE exploded
// 948KB -> 172MB (scratch streaming through HBM), kernel became memory-
// bound at 2.8TB/s (77us = 219MB/2.85TB/s). Occupancy DID reach 80% -- the
// mechanism works; the budget attribute broke it.
// Repair: __launch_bounds__(1024, 2) -- the setting that measurably left
// the allocator at ~60 VGPR / ~112 SGPR with zero spill in R8/R10. The
// ~60-VGPR live set fits the <=64 tier, so 2 blocks/CU x 16 waves =
// 32 waves/CU = 8 waves/SIMD comes from the LDS/thread limits alone.
// Instruction stream identical to R10/R11:
//   per source-pair: 6 v_fma_f32 + 1 v_min3_f32 = 3.5 VALU ops/pair,
//   coefficients in SGPRs via readfirstlane (1 SGPR operand per fma).
constexpr int BLOCKS = 512;            // 32 targets per block
constexpr int TPB = 1024;              // 16 waves
constexpr int CHUNKS = 512;            // chunk = tid & 511
constexpr int TILE = 1024;             // sources per LDS tile (16 KB float4)
constexpr int TILES = N_SRC / TILE;    // 16
constexpr int TPT = 16;                // targets per wave-half
constexpr int NROWS = N_SRC / CHUNKS;  // 32 rows per chunk overall

__global__ void zero_out(float* __restrict__ out) {
    if (threadIdx.x == 0) out[0] = 0.0f;  // d_out poisoned 0xAA each launch
}

// best = min(best, e0, e1) in one instruction (inputs never NaN here)
__device__ __forceinline__ void min3(float& b, float e0, float e1) {
    asm("v_min3_f32 %0, %0, %1, %2"
        : "+v"(b) : "v"(e0), "v"(e1));
}

// wave-uniform float -> SGPR (bit-exact; all lanes hold the same value)
__device__ __forceinline__ float to_sgpr(float x) {
    return __uint_as_float(
        (unsigned)__builtin_amdgcn_readfirstlane((int)__float_as_uint(x)));
}

__global__ __launch_bounds__(TPB, 2)
void nn13(const float* __restrict__ src,
          const float* __restrict__ tar,
          float* __restrict__ out) {
    // 64 KB: main loop double-buffers in [0, 2*TILE); tail reuses all of it
    // as fv[32][512] (64 KB of floats).
    __shared__ float4 lds[4 * TILE];

    const int tid   = threadIdx.x;
    const int g     = tid >> 9;     // 0..1: wave-uniform target half
    const int chunk = tid & 511;    // 0..511: source slice
    const int tbase = blockIdx.x * 32;

    // 16 targets per wave-half (uniform across lanes) -> coefs in SGPRs.
    float txm2[TPT], tym2[TPT], tzm2[TPT], best[TPT];
#pragma unroll
    for (int k = 0; k < TPT; ++k) {
        int T = tbase + g * TPT + k;
        txm2[k] = to_sgpr(-2.0f * tar[3 * T + 0]);
        tym2[k] = to_sgpr(-2.0f * tar[3 * T + 1]);
        tzm2[k] = to_sgpr(-2.0f * tar[3 * T + 2]);
        best[k] = INFINITY;
    }

    // ---- prolog: stage tile 0 (w = ||s||^2; exact op order matters: the
    // tail rescan replicates fmaf(x,x,fmaf(y,y,z*z)) bit-for-bit)
    {
        const float* q = src + 3 * tid;
        float x = q[0], y = q[1], z = q[2];
        lds[tid] = make_float4(x, y, z, fmaf(x, x, fmaf(y, y, z * z)));
    }
    __syncthreads();

    auto compute = [&](int cb) {
        float4 s0 = lds[cb + chunk];
        float4 s1 = lds[cb + CHUNKS + chunk];
#pragma unroll
        for (int k = 0; k < TPT; ++k) {
            float t0 = fmaf(s0.z, tzm2[k], s0.w);   // 1 SGPR operand each
            t0 = fmaf(s0.y, tym2[k], t0);
            t0 = fmaf(s0.x, txm2[k], t0);
            float t1 = fmaf(s1.z, tzm2[k], s1.w);
            t1 = fmaf(s1.y, tym2[k], t1);
            t1 = fmaf(s1.x, txm2[k], t1);
            min3(best[k], t0, t1);   // 7 VALU per 2 pairs = 3.5/pair
        }
    };

    // ---- pipelined main loop: prefetch tl+1, compute tl, write tl+1
#pragma unroll 1
    for (int tl = 0; tl < TILES - 1; ++tl) {
        const float* q = src + 3 * ((tl + 1) * TILE + tid);
        float px = q[0], py = q[1], pz = q[2];
        __builtin_amdgcn_sched_barrier(0);  // keep load issues above compute

        compute((tl & 1) * TILE);

        const int wb = ((tl + 1) & 1) * TILE;
        lds[wb + tid] = make_float4(px, py, pz,
                                    fmaf(px, px, fmaf(py, py, pz * pz)));
        __syncthreads();  // publishes writes for tl+1; retires reads of tl
    }
    compute(((TILES - 1) & 1) * TILE);

    // ---- tail: per-target reduce (value, chunk), then rescan winning chunk
    __syncthreads();                     // all compute reads of lds done
    float* fv = (float*)lds;             // [32][512] raw best values (64 KB)
#pragma unroll
    for (int k = 0; k < TPT; ++k) {
        fv[(g * TPT + k) * CHUNKS + chunk] = best[k];
    }
    __syncthreads();

    const int tprime = tid >> 5;   // 0..31: target this 32-lane group reduces
    const int sub    = tid & 31;
    float bv = fv[tprime * CHUNKS + sub];
    int   bc = sub;                // winning chunk id
#pragma unroll
    for (int m = 1; m < CHUNKS / 32; ++m) {
        float v = fv[tprime * CHUNKS + sub + 32 * m];
        if (v < bv) { bv = v; bc = sub + 32 * m; }
    }
#pragma unroll
    for (int s = 16; s >= 1; s >>= 1) {  // xor<32 stays in the aligned group
        float vv = __shfl_xor(bv, s, 64);
        int   cc = __shfl_xor(bc, s, 64);
        if (vv < bv) { bv = vv; bc = cc; }
    }
    // all 32 lanes of the group now hold (bv, bc) for target tprime.

    // ---- rescan: find the row in chunk bc whose value bit-matches bv.
    // Same fma chain as pass 1 -> the winning row reproduces bv exactly.
    const int T = tbase + tprime;
    const float tx = tar[3 * T + 0], ty = tar[3 * T + 1], tz = tar[3 * T + 2];
    const float rxm2 = -2.0f * tx, rym2 = -2.0f * ty, rzm2 = -2.0f * tz;
    int myrow;
    {
        int j = sub * CHUNKS + bc;       // row = sub (0..31), one row/lane
        const float* q = src + 3 * j;
        float x = q[0], y = q[1], z = q[2];
        float w = fmaf(x, x, fmaf(y, y, z * z));
        float v = fmaf(z, rzm2, w);
        v = fmaf(y, rym2, v);
        v = fmaf(x, rxm2, v);
        myrow = (v == bv) ? sub : NROWS;
    }
#pragma unroll
    for (int s = 16; s >= 1; s >>= 1) {
        int r2 = __shfl_xor(myrow, s, 64);
        if (r2 < myrow) myrow = r2;
    }
    __syncthreads();  // done reading fv; safe to overwrite fv[0..31]

    if (sub == 0) {
        int j = myrow * CHUNKS + bc;
        // exact loss term from the winning index (reference formula)
        float dx = src[3 * j + 0] - tx;
        float dy = src[3 * j + 1] - ty;
        float dz = src[3 * j + 2] - tz;
        fv[tprime] = 0.5f * fmaf(dx, dx, fmaf(dy, dy, dz * dz));
    }
    __syncthreads();
    if (tid == 0) {
        float ssum = 0.0f;
#pragma unroll
        for (int i = 0; i < 32; ++i) ssum += fv[i];
        atomicAdd(out, ssum);  // device-scope, cross-XCD safe
    }
}

extern "C" void kernel_launch(void* const* d_in, const int* in_sizes, int n_in,
                              void* d_out, int out_size, void* d_ws, size_t ws_size,
                              hipStream_t stream) {
    const float* src = (const float*)d_in[0];  // src_V [N,3] fp32
    const float* tar = (const float*)d_in[1];  // tar_V [M,3] fp32
    float* out = (float*)d_out;                // scalar loss fp32
    (void)d_ws; (void)ws_size;

    zero_out<<<1, 64, 0, stream>>>(out);
    nn13<<<BLOCKS, TPB, 0, stream>>>(src, tar, out);
}

// Round 8
// 85.073 us; speedup vs baseline: 1.5204x; 1.0843x over previous
//
#include <hip/hip_runtime.h>
#include <math.h>

// Problem constants (fixed by setup_inputs): N src points, M targets, D=3.
constexpr int N_SRC = 16384;
constexpr int M_TAR = 16384;

// R13: delete the barrier-synchronized tile loop entirely.
// Evidence (R9-R12): duration pinned at ~40-44us across instruction cuts
// (slope ~0.3) and occupancy knobs; R12 measured 6450 cyc/tile vs ~1800
// cyc/tile of issue -> ~65% of time in the lgkmcnt-drain + __syncthreads
// shadow at ~16 resident waves/CU. The LDS staging the barriers protect is
// pointless: the source stream is 256 KB, L2-RESIDENT (FETCH_SIZE ~900KB
// confirms HBM sees almost nothing). Guide Common-mistake #7: don't stage
// what the cache already holds.
// New structure:
//   prep:  16384 threads write (x,y,z,||s||^2) float4 -> d_ws; zero out[0].
//   nn14:  each thread streams 64 sources straight from L2 as coalesced
//          global_load_dwordx4 (lane-consecutive chunks), 2-deep register
//          pipeline, ZERO barriers in the main loop. Per source-pair cost
//          unchanged: 6 v_fma_f32 + 1 v_min3_f32 = 3.5 VALU ops/pair;
//          coefficients in SGPRs via readfirstlane.
//   LDS = 32 KB (tail reduce only) -> 4 blocks/CU, 8 waves/SIMD from the
//   2048-thread/CU limit alone. Issue floor 12.0us; L2 traffic 268MB /
//   34.5TB/s = 7.8us, overlapped. No barrier term remains.
constexpr int BLOCKS = 512;            // 32 targets per block
constexpr int TPB = 512;               // 8 waves
constexpr int CHUNKS = 256;            // chunk = tid & 255
constexpr int TPT = 16;                // targets per wave-half
constexpr int NROWS = N_SRC / CHUNKS;  // 64 rows per chunk

__global__ void prep(const float* __restrict__ src,
                     float4* __restrict__ ws,
                     float* __restrict__ out) {
    int i = blockIdx.x * blockDim.x + threadIdx.x;   // 16384 threads exact
    if (i == 0) out[0] = 0.0f;  // d_out poisoned 0xAA each launch
    const float* q = src + 3 * i;
    float x = q[0], y = q[1], z = q[2];
    // exact op order matters: nn14's rescan replicates this chain bit-for-bit
    ws[i] = make_float4(x, y, z, fmaf(x, x, fmaf(y, y, z * z)));
}

// best = min(best, e0, e1) in one instruction (inputs never NaN here)
__device__ __forceinline__ void min3(float& b, float e0, float e1) {
    asm("v_min3_f32 %0, %0, %1, %2"
        : "+v"(b) : "v"(e0), "v"(e1));
}

// wave-uniform float -> SGPR (bit-exact; all lanes hold the same value)
__device__ __forceinline__ float to_sgpr(float x) {
    return __uint_as_float(
        (unsigned)__builtin_amdgcn_readfirstlane((int)__float_as_uint(x)));
}

__global__ __launch_bounds__(TPB, 2)
void nn14(const float4* __restrict__ ws,
          const float* __restrict__ src,
          const float* __restrict__ tar,
          float* __restrict__ out) {
    __shared__ float fv[32 * CHUNKS];  // 32 KB, tail reduction only

    const int tid   = threadIdx.x;
    const int g     = tid >> 8;     // 0..1: wave-uniform target half
    const int chunk = tid & 255;    // 0..255: source slice
    const int tbase = blockIdx.x * 32;

    // 16 targets per wave-half (uniform across lanes) -> coefs in SGPRs.
    float txm2[TPT], tym2[TPT], tzm2[TPT], best[TPT];
#pragma unroll
    for (int k = 0; k < TPT; ++k) {
        int T = tbase + g * TPT + k;
        txm2[k] = to_sgpr(-2.0f * tar[3 * T + 0]);
        tym2[k] = to_sgpr(-2.0f * tar[3 * T + 1]);
        tzm2[k] = to_sgpr(-2.0f * tar[3 * T + 2]);
        best[k] = INFINITY;
    }

    auto comp = [&](float4 s0, float4 s1) {
#pragma unroll
        for (int k = 0; k < TPT; ++k) {
            float t0 = fmaf(s0.z, tzm2[k], s0.w);   // 1 SGPR operand each
            t0 = fmaf(s0.y, tym2[k], t0);
            t0 = fmaf(s0.x, txm2[k], t0);
            float t1 = fmaf(s1.z, tzm2[k], s1.w);
            t1 = fmaf(s1.y, tym2[k], t1);
            t1 = fmaf(s1.x, txm2[k], t1);
            min3(best[k], t0, t1);   // 7 VALU per 2 pairs = 3.5/pair
        }
    };

    // ---- barrier-free main loop: 2-deep register pipeline over 64 rows.
    // Lane-consecutive chunks -> consecutive 16B -> 1KB/wave dwordx4 loads.
    float4 s0 = ws[0 * CHUNKS + chunk];
    float4 s1 = ws[1 * CHUNKS + chunk];
#pragma unroll 1
    for (int r = 0; r + 2 < NROWS; r += 2) {
        float4 n0 = ws[(r + 2) * CHUNKS + chunk];
        float4 n1 = ws[(r + 3) * CHUNKS + chunk];
        __builtin_amdgcn_sched_barrier(0);  // loads issue above the compute
        comp(s0, s1);
        s0 = n0; s1 = n1;                   // vmcnt wait lands here, hidden
    }
    comp(s0, s1);

    // ---- tail: per-target reduce (value, chunk), then rescan winning chunk
#pragma unroll
    for (int k = 0; k < TPT; ++k) {
        fv[(g * TPT + k) * CHUNKS + chunk] = best[k];
    }
    __syncthreads();

    const int tprime = tid >> 4;   // 0..31: target this 16-lane group reduces
    const int sub    = tid & 15;
    float bv = fv[tprime * CHUNKS + sub];
    int   bc = sub;                // winning chunk id
#pragma unroll
    for (int m = 1; m < CHUNKS / 16; ++m) {
        float v = fv[tprime * CHUNKS + sub + 16 * m];
        if (v < bv) { bv = v; bc = sub + 16 * m; }
    }
#pragma unroll
    for (int s = 8; s >= 1; s >>= 1) {   // xor<16 stays in the 16-lane group
        float vv = __shfl_xor(bv, s, 64);
        int   cc = __shfl_xor(bc, s, 64);
        if (vv < bv) { bv = vv; bc = cc; }
    }
    // all 16 lanes of the group now hold (bv, bc) for target tprime.

    // ---- rescan: find the row in chunk bc whose value bit-matches bv.
    // Same fma chain as pass 1 (and prep) -> winning row reproduces bv.
    const int T = tbase + tprime;
    const float tx = tar[3 * T + 0], ty = tar[3 * T + 1], tz = tar[3 * T + 2];
    const float rxm2 = -2.0f * tx, rym2 = -2.0f * ty, rzm2 = -2.0f * tz;
    int myrow = NROWS;  // sentinel
#pragma unroll
    for (int rr = 0; rr < NROWS / 16; ++rr) {
        int r = sub + 16 * rr;
        int j = r * CHUNKS + bc;
        const float* q = src + 3 * j;
        float x = q[0], y = q[1], z = q[2];
        float w = fmaf(x, x, fmaf(y, y, z * z));
        float v = fmaf(z, rzm2, w);
        v = fmaf(y, rym2, v);
        v = fmaf(x, rxm2, v);
        if (v == bv && r < myrow) myrow = r;
    }
#pragma unroll
    for (int s = 8; s >= 1; s >>= 1) {
        int r2 = __shfl_xor(myrow, s, 64);
        if (r2 < myrow) myrow = r2;
    }
    __syncthreads();  // done reading fv; safe to overwrite fv[0..31]

    if (sub == 0) {
        int j = myrow * CHUNKS + bc;
        // exact loss term from the winning index (reference formula)
        float dx = src[3 * j + 0] - tx;
        float dy = src[3 * j + 1] - ty;
        float dz = src[3 * j + 2] - tz;
        fv[tprime] = 0.5f * fmaf(dx, dx, fmaf(dy, dy, dz * dz));
    }
    __syncthreads();
    if (tid == 0) {
        float ssum = 0.0f;
#pragma unroll
        for (int i = 0; i < 32; ++i) ssum += fv[i];
        atomicAdd(out, ssum);  // device-scope, cross-XCD safe
    }
}

extern "C" void kernel_launch(void* const* d_in, const int* in_sizes, int n_in,
                              void* d_out, int out_size, void* d_ws, size_t ws_size,
                              hipStream_t stream) {
    const float* src = (const float*)d_in[0];  // src_V [N,3] fp32
    const float* tar = (const float*)d_in[1];  // tar_V [M,3] fp32
    float* out = (float*)d_out;                // scalar loss fp32
    float4* ws = (float4*)d_ws;                // 256 KB: (x,y,z,||s||^2)
    (void)ws_size;

    prep<<<N_SRC / 512, 512, 0, stream>>>(src, ws, out);
    nn14<<<BLOCKS, TPB, 0, stream>>>(ws, src, tar, out);
}